// Round 3
// baseline (88.950 us; speedup 1.0000x reference)
//
#include <hip/hip_runtime.h>
#include <hip/hip_bf16.h>

// cross_set_score, fused one-pass. Shapes: x[64,64,64,256] f32, M=64 items, F=256.
// out[p,q] = out[q,p] = sum_h W2[h] * (sum_{a,b} relu(hA[a,hD:]·hB[b,hD:]))*0.125
//            / (nItem[p]*nItem[q]),  hA = x[p,q]@W1, hB = x[q,p]@W1 (bf16 in-block).
// 2080 blocks = unordered pairs; 256 thr (4 waves). Memory-bound: 268 MB x read once.

#define NSET 64
#define MITEM 64
#define FFEAT 256

typedef float f32x4 __attribute__((ext_vector_type(4)));
typedef short bf16x8 __attribute__((ext_vector_type(8)));
typedef unsigned short u16;
typedef u16 u16x4 __attribute__((ext_vector_type(4)));

__device__ __forceinline__ u16 f2bf(float f) {
    __bf16 b = (__bf16)f;
    return __builtin_bit_cast(u16, b);
}
__device__ __forceinline__ f32x4 mfma16(bf16x8 a, bf16x8 b, f32x4 c) {
    return __builtin_amdgcn_mfma_f32_16x16x32_bf16(a, b, c, 0, 0, 0);
}

// ---- prep: W1 [k=256][c=256] f32 -> W1T bf16 [c][k] (B-frags contiguous in k)
__global__ void prep_w1t_kernel(const float* __restrict__ w1, u16* __restrict__ w1t) {
    int c = blockIdx.x, k = threadIdx.x;
    w1t[c * 256 + k] = f2bf(w1[k * 256 + c]);
}

__global__ __launch_bounds__(256, 2) void fused_kernel(const float* __restrict__ x,
                                                       const u16* __restrict__ w1t,
                                                       const float* __restrict__ nItem,
                                                       const float* __restrict__ W2,
                                                       float* __restrict__ out) {
    // [64 rows][264 cols] bf16, 528 B row stride (16B-mult; 2-way bank alias = free).
    // Holds x-slice (bf16) during projection, then overwritten with h.
    __shared__ u16 BUFA[MITEM][264];   // 33.8 KiB
    __shared__ u16 BUFB[MITEM][264];   // 33.8 KiB
    __shared__ float red[4];

    int p = 0, rem = blockIdx.x;
    while (rem >= NSET - p) { rem -= NSET - p; ++p; }
    const int q = p + rem;

    const float* xA = x + (size_t)(p * NSET + q) * (MITEM * FFEAT);
    const float* xB = x + (size_t)(q * NSET + p) * (MITEM * FFEAT);

    const int tid  = threadIdx.x;
    const int lane = tid & 63;
    const int wave = tid >> 6;          // 0..3: owns 64 output cols == head `wave`
    const int ar   = lane & 15;
    const int k0   = (lane >> 4) * 8;

    // ---------------- phase 0: stage x[p,q], x[q,p] as bf16 into LDS ----------
    // 16384 f32 per slice; thread t takes float4 at f = i*1024 + t*4 (i=0..15):
    // per instr one wave covers 1 KiB contiguous (perfect coalescing).
#pragma unroll
    for (int ii = 0; ii < 16; ii += 4) {
        float4 ra[4], rb[4];
#pragma unroll
        for (int u = 0; u < 4; ++u) {
            const int f = (ii + u) * 1024 + tid * 4;
            ra[u] = *(const float4*)(xA + f);
            rb[u] = *(const float4*)(xB + f);
        }
#pragma unroll
        for (int u = 0; u < 4; ++u) {
            const int f = (ii + u) * 1024 + tid * 4;
            const int r = f >> 8, c = f & 255;
            u16x4 pa = { f2bf(ra[u].x), f2bf(ra[u].y), f2bf(ra[u].z), f2bf(ra[u].w) };
            u16x4 pb = { f2bf(rb[u].x), f2bf(rb[u].y), f2bf(rb[u].z), f2bf(rb[u].w) };
            *(u16x4*)&BUFA[r][c] = pa;
            *(u16x4*)&BUFB[r][c] = pb;
        }
    }
    __syncthreads();

    // ---------------- phase 1: project hA, hB (interleaved, share B-frags) ----
    // wave owns cols [wave*64, wave*64+64): 4 col-tiles x 4 row-tiles, K=256.
    f32x4 accA[4][4] = {}, accB[4][4] = {};
#pragma unroll
    for (int kc = 0; kc < 8; ++kc) {
        bf16x8 bu[4];
#pragma unroll
        for (int u = 0; u < 4; ++u)
            bu[u] = *(const bf16x8*)(w1t + (size_t)(wave * 64 + u * 16 + ar) * 256
                                         + kc * 32 + k0);
        bf16x8 aA[4], aB[4];
#pragma unroll
        for (int rt = 0; rt < 4; ++rt) {
            aA[rt] = *(const bf16x8*)&BUFA[rt * 16 + ar][kc * 32 + k0];
            aB[rt] = *(const bf16x8*)&BUFB[rt * 16 + ar][kc * 32 + k0];
        }
#pragma unroll
        for (int u = 0; u < 4; ++u)
#pragma unroll
            for (int rt = 0; rt < 4; ++rt) {
                accA[rt][u] = mfma16(aA[rt], bu[u], accA[rt][u]);
                accB[rt][u] = mfma16(aB[rt], bu[u], accB[rt][u]);
            }
    }
    __syncthreads();   // all XS reads done before overwrite

    // ---------------- phase 2: write h over the x staging ---------------------
    // C/D layout: col = lane&15, row = (lane>>4)*4 + j  [m89]
    const int rj = (lane >> 4) * 4;
#pragma unroll
    for (int rt = 0; rt < 4; ++rt)
#pragma unroll
        for (int u = 0; u < 4; ++u) {
            const int cc = wave * 64 + u * 16 + ar;
#pragma unroll
            for (int j = 0; j < 4; ++j) {
                BUFA[rt * 16 + rj + j][cc] = f2bf(accA[rt][u][j]);
                BUFB[rt * 16 + rj + j][cc] = f2bf(accB[rt][u][j]);
            }
        }
    __syncthreads();

    // ---------------- phase 3: score head `wave`: relu-sum of hA_h @ hB_h^T ---
    const int hc = wave * 64;
    bf16x8 aS[4][2];
#pragma unroll
    for (int rt = 0; rt < 4; ++rt)
#pragma unroll
        for (int kk = 0; kk < 2; ++kk)
            aS[rt][kk] = *(const bf16x8*)&BUFA[rt * 16 + ar][hc + kk * 32 + k0];

    float sum = 0.f;
#pragma unroll
    for (int bu = 0; bu < 4; ++bu) {
        bf16x8 b0 = *(const bf16x8*)&BUFB[bu * 16 + ar][hc + k0];
        bf16x8 b1 = *(const bf16x8*)&BUFB[bu * 16 + ar][hc + 32 + k0];
#pragma unroll
        for (int rt = 0; rt < 4; ++rt) {
            f32x4 c = {};
            c = mfma16(aS[rt][0], b0, c);
            c = mfma16(aS[rt][1], b1, c);   // full k=64 BEFORE relu
            sum += fmaxf(c[0], 0.f) + fmaxf(c[1], 0.f) +
                   fmaxf(c[2], 0.f) + fmaxf(c[3], 0.f);
        }
    }

    // ---------------- phase 4: reduce + output --------------------------------
#pragma unroll
    for (int off = 32; off; off >>= 1) sum += __shfl_xor(sum, off);
    if (lane == 0) red[wave] = sum;
    __syncthreads();
    if (tid == 0) {
        const float nP = nItem[p], nQ = nItem[q];
        float v = 0.f;
#pragma unroll
        for (int h = 0; h < 4; ++h)
            v += (((red[h] * 0.125f) / nQ) / nP) * W2[h];
        out[p * NSET + q] = v;
        out[q * NSET + p] = v;
    }
}

extern "C" void kernel_launch(void* const* d_in, const int* in_sizes, int n_in,
                              void* d_out, int out_size, void* d_ws, size_t ws_size,
                              hipStream_t stream) {
    const float* x     = (const float*)d_in[0];
    const float* nItem = (const float*)d_in[1];
    const float* W1    = (const float*)d_in[2];
    const float* W2    = (const float*)d_in[3];
    float* out = (float*)d_out;

    u16* w1t = (u16*)d_ws;                 // 128 KiB
    if (ws_size < 131072) return;

    hipLaunchKernelGGL(prep_w1t_kernel, dim3(256), dim3(256), 0, stream, W1, w1t);
    hipLaunchKernelGGL(fused_kernel, dim3(2080), dim3(256), 0, stream,
                       x, w1t, nItem, W2, out);
}